// Round 9
// baseline (87.981 us; speedup 1.0000x reference)
//
#include <hip/hip_runtime.h>

#define BATCH   32
#define SEQ     2048
#define MDIM    128
#define LBAS    64
#define NW      2041        // SEQ - RANK + 1
#define APAD    136         // bf16 elems per sA row
#define NBLK    512         // 32 batches x 16 groups of 128 windows
#define NPASS   3           // DIAGNOSTIC: 3 identical passes, result /3

typedef __attribute__((ext_vector_type(8))) short  short8;
typedef __attribute__((ext_vector_type(4))) float  float4v;
typedef __attribute__((ext_vector_type(2))) float  float2v;

__device__ __forceinline__ unsigned short f2bf(float f) {
    unsigned int u = __float_as_uint(f);
    return (unsigned short)((u + 0x7FFFu + ((u >> 16) & 1u)) >> 16);
}

// ---------------------------------------------------------------------------
// Prep: M -> bf16 B-fragment-linear Mb[(k>>3)*128+n][j];
//       nkT[n][k] = Acoeff[n][k] * Bbasis[k][n]   (TRANSPOSED: main loads f4)
// ---------------------------------------------------------------------------
__global__ __launch_bounds__(256)
void ndd_prep(const float* __restrict__ Mmat,
              const float* __restrict__ Acoeff,
              const float* __restrict__ Bbasis,
              unsigned short* __restrict__ Mb,
              float* __restrict__ nkT)
{
    const int gid = blockIdx.x * 256 + threadIdx.x;
    if (gid < 2048) {                    // 128 rows x 16 k-chunks
        const int n = gid >> 4;
        const int c = gid & 15;
        const float* src = Mmat + n * MDIM + c * 8;
        short8 v;
        #pragma unroll
        for (int j = 0; j < 8; ++j) v[j] = (short)f2bf(src[j]);
        *reinterpret_cast<short8*>(Mb + ((size_t)(c * MDIM + n)) * 8) = v;
    } else if (gid < 2048 + 8192) {      // nkT: [128][64]
        const int e = gid - 2048;
        const int n = e >> 6;
        const int k = e & 63;
        nkT[e] = Acoeff[e] * Bbasis[k * MDIM + n];   // Acoeff is [n][k] too
    }
}

// ---------------------------------------------------------------------------
// Main (R16): *** DIAGNOSTIC ROUND — deliberately 3x work ***
// Session state: R0..R8 plateau at 83-90 (noise +-3); two structurally
// opposite mains (16-barrier staged pipeline vs barrier-free register
// sliding-window) both decompose to ~31-34us vs a ~7-10us HBM roofline --
// and ndd_main has NEVER appeared in the harness's top-5 counter rows (the
// ~43us 256MiB harness fills mask it), so no theory about it has ever been
// counter-checked. This round runs the R8 sliding-window body NPASS=3 times
// (accumulate local, scale by 1/3; passes 2-3 re-fetch each block's 80KB
// x-region from L2/L3; unroll-1 + barriers prevent cross-pass CSE) purely
// to force main into the top-5 and finally read its FETCH_SIZE / VALUBusy /
// MfmaUtil / OccupancyPercent / SQ_LDS_BANK_CONFLICT / VGPR_Count.
// Numerics: sum of 3 identical pass-sums * (1/3) differs from one pass by
// ~1ulp (<<2.5e-3 threshold).
// Pre-committed forks: 3x dur ~55-65 + low util -> latency-bound -> slim
// (256,4)/1024blk next; ~35-42 -> cold-HBM/first-touch -> occupancy/
// prefetch; VALUBusy>50% or big bank-conflict -> phase2/LDS is the cost;
// still absent from top-5 -> main <15us, subtraction model wrong ->
// harness-dominated, declare roofline.
// Ledger: R1 de-persist 90.5 | R2 (256,3)+1024blk 86.3 | R3 coop sync
// broken | R4 inline-prep 88.5 | R5 atomic 87.1 | R6 R0-control 85.5 |
// R7 infra fail | R8 sliding-window 84.0 (= noise).
// ---------------------------------------------------------------------------
__global__ __launch_bounds__(256, 2)
void ndd_main(const float* __restrict__ x,            // [32][2048][128]
              const unsigned short* __restrict__ Mb,  // bf16 frag-linear
              const float* __restrict__ nkT,          // [128][64]
              float* __restrict__ partial)            // [512]
{
    __shared__ __align__(16) unsigned short sA[128 * APAD];   // 34 KB
    __shared__ float sred[4];

    const int tid  = threadIdx.x;
    const int lane = tid & 63;
    const int wave = tid >> 6;
    const int b    = blockIdx.x >> 4;          // batch
    const int base = (blockIdx.x & 15) * 128;  // window base (mult of 128)
    const float* xb = x + (size_t)b * SEQ * MDIM;

    const int l15 = lane & 15;
    const int q   = lane >> 4;
    const int nb  = wave * 32;                 // this wave's n-columns

    // ---- tile-invariant hoists (outside the pass loop) ----
    short8 bfr[4][2];
    #pragma unroll
    for (int kk = 0; kk < 4; ++kk)
        #pragma unroll
        for (int nj = 0; nj < 2; ++nj)
            bfr[kk][nj] = *reinterpret_cast<const short8*>(
                Mb + ((size_t)((kk * 4 + q) * MDIM + nb + nj * 16 + l15)) * 8);
    float4v nkreg[4][2];
    #pragma unroll
    for (int p = 0; p < 4; ++p)
        #pragma unroll
        for (int nj = 0; nj < 2; ++nj)
            nkreg[p][nj] = *reinterpret_cast<const float4v*>(
                nkT + (size_t)(nb + nj * 16 + l15) * LBAS + p * 16 + q * 4);

    float local = 0.f;

    #pragma unroll 1
    for (int pass = 0; pass < NPASS; ++pass) {
        if (pass) __syncthreads();             // WAR hygiene on sA re-write

        // ---- 39 coalesced row loads -> registers ----
        const int r0 = base + wave * 32;
        float2v rows[39];
        #pragma unroll
        for (int k = 0; k < 39; ++k) {
            int rr = r0 + k;
            rr = rr > 2047 ? 2047 : rr;        // tail clamp (masked later)
            rows[k] = *reinterpret_cast<const float2v*>(
                xb + (size_t)rr * MDIM + lane * 2);
        }

        // ---- sliding-window means -> bf16 sA (thread owns 2 cols) ----
        unsigned short* myA = sA + (size_t)(wave * 32) * APAD + lane * 2;
        float2v s = ((rows[0] + rows[1]) + (rows[2] + rows[3])) +
                    ((rows[4] + rows[5]) + (rows[6] + rows[7]));
        {
            float2v m = s * 0.125f;
            *reinterpret_cast<unsigned int*>(myA) =
                (unsigned)f2bf(m.x) | ((unsigned)f2bf(m.y) << 16);
        }
        #pragma unroll
        for (int w = 1; w < 32; ++w) {
            s += rows[w + 7] - rows[w - 1];
            float2v m = s * 0.125f;
            *reinterpret_cast<unsigned int*>(myA + (size_t)w * APAD) =
                (unsigned)f2bf(m.x) | ((unsigned)f2bf(m.y) << 16);
        }

        __syncthreads();

        // ---- MFMA + epilogue over 8 window-groups ----
        #pragma unroll
        for (int wg = 0; wg < 8; ++wg) {
            float4v accf[2] = {(float4v){0.f,0.f,0.f,0.f},
                               (float4v){0.f,0.f,0.f,0.f}};
            #pragma unroll
            for (int kk = 0; kk < 4; ++kk) {
                const short8 af = *reinterpret_cast<const short8*>(
                    &sA[(wg * 16 + l15) * APAD + kk * 32 + q * 8]);
                #pragma unroll
                for (int nj = 0; nj < 2; ++nj)
                    accf[nj] = __builtin_amdgcn_mfma_f32_16x16x32_bf16(
                        af, bfr[kk][nj], accf[nj], 0, 0, 0);
            }
            const int p = wg & 3;              // kmod = (wg%4)*16 + q*4 + r
            #pragma unroll
            for (int nj = 0; nj < 2; ++nj) {
                #pragma unroll
                for (int r = 0; r < 4; ++r) {
                    const int w = base + wg * 16 + q * 4 + r;
                    if (w < NW) {
                        const float d = accf[nj][r] - nkreg[p][nj][r];
                        local += d * d;
                    }
                }
            }
        }
    }

    // ---- block reduce -> one partial (scaled by 1/NPASS) ----
    #pragma unroll
    for (int off = 32; off > 0; off >>= 1)
        local += __shfl_down(local, off, 64);
    if (lane == 0) sred[wave] = local;
    __syncthreads();
    if (tid == 0)
        partial[blockIdx.x] = ((sred[0] + sred[1]) + (sred[2] + sred[3]))
                              * (1.0f / (float)NPASS);
}

// ---------------------------------------------------------------------------
// Final reduce: 512 partials -> scalar D
// ---------------------------------------------------------------------------
__global__ __launch_bounds__(256)
void ndd_reduce(const float* __restrict__ partial, float* __restrict__ out)
{
    __shared__ float sred[4];
    float s = partial[threadIdx.x] + partial[threadIdx.x + 256];
    #pragma unroll
    for (int off = 32; off > 0; off >>= 1) s += __shfl_down(s, off, 64);
    if ((threadIdx.x & 63) == 0) sred[threadIdx.x >> 6] = s;
    __syncthreads();
    if (threadIdx.x == 0)
        out[0] = ((sred[0] + sred[1]) + (sred[2] + sred[3])) * (1.0f / 8359936.0f);
}

extern "C" void kernel_launch(void* const* d_in, const int* in_sizes, int n_in,
                              void* d_out, int out_size, void* d_ws, size_t ws_size,
                              hipStream_t stream) {
    const float* x     = (const float*)d_in[0];
    const float* Mmat  = (const float*)d_in[1];
    const float* Acoef = (const float*)d_in[2];
    const float* Bbas  = (const float*)d_in[3];
    float* out         = (float*)d_out;

    unsigned short* Mb = (unsigned short*)d_ws;             // 32 KB bf16
    float* nkTp        = (float*)((char*)d_ws + 32768);     // 32 KB fp32
    float* part        = (float*)((char*)d_ws + 65536);     // 2 KB partials

    ndd_prep<<<40, 256, 0, stream>>>(Mmat, Acoef, Bbas, Mb, nkTp);
    ndd_main<<<NBLK, 256, 0, stream>>>(x, Mb, nkTp, part);
    ndd_reduce<<<1, 256, 0, stream>>>(part, out);
}